// Round 11
// baseline (249.685 us; speedup 1.0000x reference)
//
#include <hip/hip_runtime.h>
#include <hip/hip_bf16.h>

#define N_NODES 50000
#define N_EDGES 800000
#define FEAT    128
#define N_TILES (N_NODES / 16)          // 3125
#define GEMM_BLOCKS 784                  // 782 needed (3125/4), padded to mult of 8
#define MAXD    32                       // slots per node; Poisson(16) P(deg>=32)~1e-4
#define OVF_CAP 16384
#define NODES_PER_GRP 6250               // 50000 / 8
#define CHUNK   2048
#define NCHUNK  ((N_EDGES + CHUNK - 1) / CHUNK)   // 391
#define QCAP    110000                   // per-group queue capacity (mean 100K, sigma~300)
#define SCAT_BPG 98                      // scatter blocks per group -> 784 total
#define AGG_QB  1563                     // agg node-quad blocks per slice
#define SLICE_U 400000                   // uints per hidden slice (50000*16 ushort)

using short8  = __attribute__((ext_vector_type(8))) short;
using float4v = __attribute__((ext_vector_type(4))) float;

// ---------------- workspace layout (bytes) ----------------
// flag int[256] @0  (flag[1]=ovf cursor; flag[16+16g]=group-g queue cursor, one/line)
// fill int[50048] @1024 | ovf int2[16384] @201216 | slots uint[50000*32] @332288
// hidden ushort[8][50000][16] @6732288 (SLICE-MAJOR) | queue int2[8*QCAP] @19532288
// wbf ushort[16384] @26572288 (bf16 W, pre-swizzled chunks)   total ~26.6 MB

__device__ __forceinline__ unsigned short f2b(float f) {
    __hip_bfloat16 h = __float2bfloat16(f);           // RNE
    return __builtin_bit_cast(unsigned short, h);
}

// k_prep: zero flag[256]+fill[50048] AND convert W f32->bf16 into wbf with the
// 16B-chunk XOR swizzle (chunk cc of row r stored at cc^(r&7)). k_fused then
// copies wbf LINEARLY into LDS and applies the same XOR on reads.
__global__ __launch_bounds__(256) void k_prep(const float* __restrict__ W,
                                              int* __restrict__ ws_ints,
                                              unsigned short* __restrict__ wbf) {
    const int gid = blockIdx.x * 256 + threadIdx.x;
    if (gid < 12576) ((int4*)ws_ints)[gid] = make_int4(0, 0, 0, 0);  // 50304 ints
    if (gid < 2048) {                                 // 2048 chunks of 8 elems
        const int r  = gid >> 4;
        const int cc = gid & 15;
        const float* s = W + (size_t)r * FEAT + cc * 8;
        float4v a0 = *(const float4v*)(s);
        float4v a1 = *(const float4v*)(s + 4);
        short8 v;
        #pragma unroll
        for (int j = 0; j < 4; ++j) { v[j] = (short)f2b(a0[j]); v[4 + j] = (short)f2b(a1[j]); }
        const int dst = r * 16 + (cc ^ (r & 7));      // swizzled chunk slot
        *(short8*)(wbf + (size_t)dst * 8) = v;
    }
}

// k1: blocks [0,GEMM_BLOCKS) = GEMM (R6-proven shape; staging from pre-swizzled
//     bf16 wbf). Epilogue stores hidden SLICE-MAJOR (slice=col/16) so k_agg's
//     per-XCD gather working set is a contiguous 1.6MB (L2-resident).
//     blocks [GEMM_BLOCKS, +NCHUNK) = partition pass (R3's 100K same-line
//     atomics lesson: LDS-aggregate, 8 padded-line global atomics/block).
__global__ __launch_bounds__(256) void k_fused(const float* __restrict__ x,
                                               const unsigned short* __restrict__ wbf,
                                               const float* __restrict__ bias,
                                               unsigned short* __restrict__ hidden,
                                               const int* __restrict__ ei,
                                               const float* __restrict__ wt,
                                               int* __restrict__ flag,
                                               int2* __restrict__ queue) {
    __shared__ __align__(16) unsigned short Wlds[128 * 128];   // 32KB
    const int t = threadIdx.x;

    if (blockIdx.x < GEMM_BLOCKS) {
        // ---------------- GEMM path ----------------
        #pragma unroll
        for (int j = 0; j < 8; ++j) {                 // 2048 chunks / 256 thr
            const int c16 = j * 256 + t;
            *(short8*)&Wlds[c16 * 8] = *(const short8*)(wbf + (size_t)c16 * 8);
        }
        __syncthreads();

        const int wave = t >> 6;
        const int lane = t & 63;
        int tile = blockIdx.x * 4 + wave;
        if (tile >= N_TILES) tile = N_TILES - 1;    // clamp: redundant work, no divergent exit
        const int rowBase = tile * 16;
        const int m    = lane & 15;
        const int quad = lane >> 4;

        float4v acc[8];
        #pragma unroll
        for (int i = 0; i < 8; ++i) acc[i] = (float4v){0.f, 0.f, 0.f, 0.f};

        #pragma unroll
        for (int kk = 0; kk < 4; ++kk) {
            const int k0 = kk * 32 + quad * 8;
            const float* ap = x + (size_t)(rowBase + m) * FEAT + k0;
            float4v a0 = *(const float4v*)(ap);
            float4v a1 = *(const float4v*)(ap + 4);
            short8 af;
            #pragma unroll
            for (int j = 0; j < 4; ++j) { af[j] = (short)f2b(a0[j]); af[4 + j] = (short)f2b(a1[j]); }
            const int cc = kk * 4 + quad;             // chunk col index k0/8
            #pragma unroll
            for (int nt = 0; nt < 8; ++nt) {
                const int rr = nt * 16 + m;
                short8 bf = *(const short8*)&Wlds[rr * 128 + ((cc ^ (rr & 7)) << 3)];
                acc[nt] = __builtin_amdgcn_mfma_f32_16x16x32_bf16(af, bf, acc[nt], 0, 0, 0);
            }
        }

        const int r0 = rowBase + quad * 4;          // C/D: col=lane&15, row=quad*4+r
        #pragma unroll
        for (int nt = 0; nt < 8; ++nt) {            // slice-major: slice == nt
            const int col = nt * 16 + m;
            const float bc = bias[col];
            unsigned short* hp = hidden + (size_t)nt * 800000 + (size_t)r0 * 16 + m;
            #pragma unroll
            for (int r = 0; r < 4; ++r) {
                hp[r * 16] = f2b(acc[nt][r] + bc);
            }
        }
    } else {
        // ---------------- partition pass (LDS-aggregated) ----------------
        int* lcnt  = (int*)Wlds;                     // [8] per-group local counts
        int* gbase = lcnt + 8;                       // [8] per-group global bases
        const int bid  = blockIdx.x - GEMM_BLOCKS;   // chunk id, 0..390
        const int lane = t & 63;

        // per-wave int64-vs-int32 detection (int64: odd words of first 64 are 0)
        unsigned long long mball = __ballot(ei[2 * lane + 1] != 0);
        const int sh = (mball == 0ULL) ? 1 : 0;

        if (t < 8) lcnt[t] = 0;
        __syncthreads();

        const int e0 = bid * CHUNK + t;
        int      dstv[8];
        unsigned recv_[8];
        int      lpos[8];
        #pragma unroll
        for (int i = 0; i < 8; ++i) {
            int e = e0 + i * 256;
            if (e < N_EDGES) {
                int dst = ei[(size_t)e << sh];
                if ((unsigned)dst >= N_NODES) dst = 0;
                int src = ei[(size_t)(N_EDGES + e) << sh];
                if ((unsigned)src >= N_NODES) src = 0;
                dstv[i]  = dst;
                recv_[i] = ((unsigned)f2b(wt[e]) << 16) | (unsigned)src;
                lpos[i]  = atomicAdd(&lcnt[dst / NODES_PER_GRP], 1);
            } else {
                dstv[i] = -1;
            }
        }
        __syncthreads();
        if (t < 8) gbase[t] = atomicAdd(&flag[16 + 16 * t], lcnt[t]);
        __syncthreads();

        #pragma unroll
        for (int i = 0; i < 8; ++i) {
            if (dstv[i] < 0) continue;
            int g   = dstv[i] / NODES_PER_GRP;
            int idx = gbase[g] + lpos[i];
            if (idx < QCAP) {
                int2 r; r.x = dstv[i]; r.y = (int)recv_[i];
                queue[(size_t)g * QCAP + idx] = r;
            }
        }
    }
}

// k2: XCD-local scatter, 4x ILP.
__global__ __launch_bounds__(256) void k_scat(const int2* __restrict__ queue,
                                              int* __restrict__ flag,
                                              int* __restrict__ fill,
                                              unsigned int* __restrict__ slots,
                                              int2* __restrict__ ovf) {
    const int g = blockIdx.x & 7;                    // == XCD (round-robin dispatch)
    const int b = blockIdx.x >> 3;                   // 0..SCAT_BPG-1
    int n = flag[16 + 16 * g]; if (n > QCAP) n = QCAP;
    const int2* q = queue + (size_t)g * QCAP;
    const int stride = SCAT_BPG * 256;

    int i = b * 256 + (int)threadIdx.x;
    for (; i + 3 * stride < n; i += 4 * stride) {
        int2 e0 = q[i];
        int2 e1 = q[i + stride];
        int2 e2 = q[i + 2 * stride];
        int2 e3 = q[i + 3 * stride];
        int p0 = atomicAdd(&fill[e0.x], 1);
        int p1 = atomicAdd(&fill[e1.x], 1);
        int p2 = atomicAdd(&fill[e2.x], 1);
        int p3 = atomicAdd(&fill[e3.x], 1);
        if (p0 < MAXD) slots[(size_t)e0.x * MAXD + p0] = (unsigned)e0.y;
        else { int op = atomicAdd(&flag[1], 1); if (op < OVF_CAP) ovf[op] = e0; }
        if (p1 < MAXD) slots[(size_t)e1.x * MAXD + p1] = (unsigned)e1.y;
        else { int op = atomicAdd(&flag[1], 1); if (op < OVF_CAP) ovf[op] = e1; }
        if (p2 < MAXD) slots[(size_t)e2.x * MAXD + p2] = (unsigned)e2.y;
        else { int op = atomicAdd(&flag[1], 1); if (op < OVF_CAP) ovf[op] = e2; }
        if (p3 < MAXD) slots[(size_t)e3.x * MAXD + p3] = (unsigned)e3.y;
        else { int op = atomicAdd(&flag[1], 1); if (op < OVF_CAP) ovf[op] = e3; }
    }
    for (; i < n; i += stride) {
        int2 ent = q[i];
        int pos = atomicAdd(&fill[ent.x], 1);
        if (pos < MAXD) slots[(size_t)ent.x * MAXD + pos] = (unsigned)ent.y;
        else { int op = atomicAdd(&flag[1], 1); if (op < OVF_CAP) ovf[op] = ent; }
    }
}

// k3: column-sliced aggregation. Block bid%8 == slice s (round-robin -> XCD s)
// handles cols [s*16, s*16+16) for all nodes: its gathers hit ONLY the
// contiguous 1.6MB hidden slice (L2-resident). slots/fill read via nontemporal
// loads (8x re-read, streaming) so they don't evict the hot slice.
// Per wave: 8 lane-groups of 8; group g handles edges e%8==g; lane reads 4B
// (2 bf16 cols). Reduce over groups via shfl_xor 8/16/32.
__global__ __launch_bounds__(256) void k_agg(const int* __restrict__ fill,
                                             const unsigned int* __restrict__ slots,
                                             const unsigned int* __restrict__ hid,
                                             const int* __restrict__ flag,
                                             const int2* __restrict__ ovf,
                                             float* __restrict__ out) {
    const int wave  = threadIdx.x >> 6;
    const int lane  = threadIdx.x & 63;
    const int slice = blockIdx.x & 7;
    const int qb    = blockIdx.x >> 3;              // 0..AGG_QB-1
    const int g8    = lane >> 3;                    // edge group 0..7
    const int c2    = lane & 7;                     // col pair within slice
    const unsigned* hs = hid + (size_t)slice * SLICE_U;

    int novf = -1;                                   // lazy-loaded ovf count

    for (int node = qb * 4 + wave; node < N_NODES; node += AGG_QB * 4) {
        const int degf = __builtin_nontemporal_load(fill + node);
        const int deg  = (degf > MAXD) ? MAXD : degf;
        const unsigned* sl = slots + (size_t)node * MAXD;

        float a0 = 0.f, a1 = 0.f;
        const int iters = (deg + 7) >> 3;           // 0..4
        for (int it = 0; it < iters; it += 2) {
            const int ea = it * 8 + g8;
            const int eb = ea + 8;
            unsigned ra = __builtin_nontemporal_load(sl + ea);
            unsigned rb = __builtin_nontemporal_load(sl + (eb & 31));
            const bool va = ea < deg;
            const bool vb = eb < deg;
            const float    wa = va ? __uint_as_float(ra & 0xffff0000u) : 0.f;
            const float    wb = vb ? __uint_as_float(rb & 0xffff0000u) : 0.f;
            const unsigned sa = va ? (ra & 0xffffu) : 0u;
            const unsigned sb = vb ? (rb & 0xffffu) : 0u;
            unsigned ha = hs[(size_t)sa * 8 + c2];  // 4B gather, L2-resident slice
            unsigned hb = hs[(size_t)sb * 8 + c2];
            a0 = fmaf(wa, __uint_as_float((ha & 0xffffu) << 16), a0);
            a1 = fmaf(wa, __uint_as_float(ha & 0xffff0000u),     a1);
            a0 = fmaf(wb, __uint_as_float((hb & 0xffffu) << 16), a0);
            a1 = fmaf(wb, __uint_as_float(hb & 0xffff0000u),     a1);
        }

        if (degf > MAXD) {                           // rare overflow edges
            if (novf < 0) { novf = flag[1]; if (novf > OVF_CAP) novf = OVF_CAP; }
            for (int i = 0; i < novf; ++i) {
                int2 r = ovf[i];
                if (r.x != node || (i & 7) != g8) continue;
                unsigned rec = (unsigned)r.y;
                float w = __uint_as_float(rec & 0xffff0000u);
                unsigned src = rec & 0xffffu;
                unsigned h = hs[(size_t)src * 8 + c2];
                a0 = fmaf(w, __uint_as_float((h & 0xffffu) << 16), a0);
                a1 = fmaf(w, __uint_as_float(h & 0xffff0000u),     a1);
            }
        }

        // reduce the 8 edge-groups: butterfly over lane bits 3,4,5
        a0 += __shfl_xor(a0, 8, 64);  a1 += __shfl_xor(a1, 8, 64);
        a0 += __shfl_xor(a0, 16, 64); a1 += __shfl_xor(a1, 16, 64);
        a0 += __shfl_xor(a0, 32, 64); a1 += __shfl_xor(a1, 32, 64);

        if (lane < 8) {                              // 8 lanes x 8B = 64B/node-slice
            unsigned long long p = ((unsigned long long)__float_as_uint(a1) << 32)
                                 | (unsigned long long)__float_as_uint(a0);
            __builtin_nontemporal_store(p, (unsigned long long*)
                (out + (size_t)node * FEAT + slice * 16 + c2 * 2));
        }
    }
}

extern "C" void kernel_launch(void* const* d_in, const int* in_sizes, int n_in,
                              void* d_out, int out_size, void* d_ws, size_t ws_size,
                              hipStream_t stream) {
    const float* x  = (const float*)d_in[0];
    const int*   ei = (const int*)d_in[1];
    const float* ew = (const float*)d_in[2];
    const float* W  = (const float*)d_in[3];
    const float* b  = (const float*)d_in[4];
    float* out = (float*)d_out;

    int*  flag = (int*)d_ws;                          // int[256], cursors padded
    int*  fill = flag + 256;
    int2* ovf  = (int2*)(fill + 50048);
    unsigned int* slots = (unsigned int*)(ovf + OVF_CAP);
    unsigned short* hidden = (unsigned short*)(slots + (size_t)N_NODES * MAXD);
    int2* queue = (int2*)(hidden + (size_t)N_NODES * FEAT);
    unsigned short* wbf = (unsigned short*)(queue + (size_t)8 * QCAP);

    k_prep <<<64, 256, 0, stream>>>(W, flag, wbf);    // zero cursors+fill, swizzled bf16 W
    k_fused<<<GEMM_BLOCKS + NCHUNK, 256, 0, stream>>>(x, wbf, b, hidden, ei, ew,
                                                      flag, queue);
    k_scat <<<8 * SCAT_BPG, 256, 0, stream>>>(queue, flag, fill, slots, ovf);
    k_agg  <<<AGG_QB * 8, 256, 0, stream>>>(fill, slots, (const unsigned int*)hidden,
                                            flag, ovf, out);
}

// Round 12
// 165.324 us; speedup vs baseline: 1.5103x; 1.5103x over previous
//
#include <hip/hip_runtime.h>
#include <hip/hip_bf16.h>

#define N_NODES 50000
#define N_EDGES 800000
#define FEAT    128
#define N_TILES (N_NODES / 16)          // 3125
#define GEMM_BLOCKS 784                  // 782 needed (3125/4), padded to mult of 8
#define MAXD    32                       // slots per node; Poisson(16) P(deg>=32)~1e-4
#define OVF_CAP 16384
#define NODES_PER_GRP 6250               // 50000 / 8
#define CHUNK   2048
#define NCHUNK  ((N_EDGES + CHUNK - 1) / CHUNK)   // 391
#define QCAP    110000                   // per-group queue capacity (mean 100K, sigma~300)
#define SCAT_BPG 98                      // scatter blocks per group -> 784 total
#define AGG_QPG 1563                     // agg node-quad blocks per group (6250/4 up)

using short8  = __attribute__((ext_vector_type(8))) short;
using float4v = __attribute__((ext_vector_type(4))) float;

// ---------------- workspace layout (bytes) ----------------
// flag int[256] @0  (flag[1]=ovf cursor; flag[16+16g]=group-g queue cursor, one/line)
// fill int[50048] @1024 | ovf int2[16384] @201216 | slots uint[50000*32] @332288
// hidden ushort[50000*128] @6732288 | queue int2[8*QCAP] @19532288
// wbf ushort[16384] @26572288 (bf16 W, pre-swizzled chunks)   total ~26.6 MB

__device__ __forceinline__ unsigned short f2b(float f) {
    __hip_bfloat16 h = __float2bfloat16(f);           // RNE
    return __builtin_bit_cast(unsigned short, h);
}

// k_prep: zero flag[256]+fill[50048] AND convert W f32->bf16 into wbf with the
// 16B-chunk XOR swizzle (chunk cc of row r stored at cc^(r&7)). k_fused then
// copies wbf LINEARLY into LDS and applies the same XOR on reads.
__global__ __launch_bounds__(256) void k_prep(const float* __restrict__ W,
                                              int* __restrict__ ws_ints,
                                              unsigned short* __restrict__ wbf) {
    const int gid = blockIdx.x * 256 + threadIdx.x;
    if (gid < 12576) ((int4*)ws_ints)[gid] = make_int4(0, 0, 0, 0);  // 50304 ints
    if (gid < 2048) {                                 // 2048 chunks of 8 elems
        const int r  = gid >> 4;
        const int cc = gid & 15;
        const float* s = W + (size_t)r * FEAT + cc * 8;
        float4v a0 = *(const float4v*)(s);
        float4v a1 = *(const float4v*)(s + 4);
        short8 v;
        #pragma unroll
        for (int j = 0; j < 4; ++j) { v[j] = (short)f2b(a0[j]); v[4 + j] = (short)f2b(a1[j]); }
        const int dst = r * 16 + (cc ^ (r & 7));      // swizzled chunk slot
        *(short8*)(wbf + (size_t)dst * 8) = v;
    }
}

// k1: blocks [0,GEMM_BLOCKS) = GEMM (R6-proven shape: 784 blocks, 1 tile/wave,
//     LDS-staged W from pre-swizzled bf16 wbf — 5 experiments confirmed this
//     path is latency-hidden; do not restructure).
//     blocks [GEMM_BLOCKS, +NCHUNK) = partition pass (R3's 100K same-line
//     atomics lesson: LDS-aggregate, 8 padded-line global atomics/block).
__global__ __launch_bounds__(256) void k_fused(const float* __restrict__ x,
                                               const unsigned short* __restrict__ wbf,
                                               const float* __restrict__ bias,
                                               unsigned short* __restrict__ hidden,
                                               const int* __restrict__ ei,
                                               const float* __restrict__ wt,
                                               int* __restrict__ flag,
                                               int2* __restrict__ queue) {
    __shared__ __align__(16) unsigned short Wlds[128 * 128];   // 32KB
    const int t = threadIdx.x;

    if (blockIdx.x < GEMM_BLOCKS) {
        // ---------------- GEMM path ----------------
        #pragma unroll
        for (int j = 0; j < 8; ++j) {                 // 2048 chunks / 256 thr
            const int c16 = j * 256 + t;
            *(short8*)&Wlds[c16 * 8] = *(const short8*)(wbf + (size_t)c16 * 8);
        }
        __syncthreads();

        const int wave = t >> 6;
        const int lane = t & 63;
        int tile = blockIdx.x * 4 + wave;
        if (tile >= N_TILES) tile = N_TILES - 1;    // clamp: redundant work, no divergent exit
        const int rowBase = tile * 16;
        const int m    = lane & 15;
        const int quad = lane >> 4;

        float4v acc[8];
        #pragma unroll
        for (int i = 0; i < 8; ++i) acc[i] = (float4v){0.f, 0.f, 0.f, 0.f};

        #pragma unroll
        for (int kk = 0; kk < 4; ++kk) {
            const int k0 = kk * 32 + quad * 8;
            const float* ap = x + (size_t)(rowBase + m) * FEAT + k0;
            float4v a0 = *(const float4v*)(ap);
            float4v a1 = *(const float4v*)(ap + 4);
            short8 af;
            #pragma unroll
            for (int j = 0; j < 4; ++j) { af[j] = (short)f2b(a0[j]); af[4 + j] = (short)f2b(a1[j]); }
            const int cc = kk * 4 + quad;             // chunk col index k0/8
            #pragma unroll
            for (int nt = 0; nt < 8; ++nt) {
                const int rr = nt * 16 + m;
                short8 bf = *(const short8*)&Wlds[rr * 128 + ((cc ^ (rr & 7)) << 3)];
                acc[nt] = __builtin_amdgcn_mfma_f32_16x16x32_bf16(af, bf, acc[nt], 0, 0, 0);
            }
        }

        const int r0 = rowBase + quad * 4;          // C/D: col=lane&15, row=quad*4+r
        #pragma unroll
        for (int nt = 0; nt < 8; ++nt) {
            const int col = nt * 16 + m;
            const float bc = bias[col];
            #pragma unroll
            for (int r = 0; r < 4; ++r) {
                hidden[(size_t)(r0 + r) * FEAT + col] = f2b(acc[nt][r] + bc);
            }
        }
    } else {
        // ---------------- partition pass (LDS-aggregated) ----------------
        int* lcnt  = (int*)Wlds;                     // [8] per-group local counts
        int* gbase = lcnt + 8;                       // [8] per-group global bases
        const int bid  = blockIdx.x - GEMM_BLOCKS;   // chunk id, 0..390
        const int lane = t & 63;

        // per-wave int64-vs-int32 detection (int64: odd words of first 64 are 0)
        unsigned long long mball = __ballot(ei[2 * lane + 1] != 0);
        const int sh = (mball == 0ULL) ? 1 : 0;

        if (t < 8) lcnt[t] = 0;
        __syncthreads();

        const int e0 = bid * CHUNK + t;
        int      dstv[8];
        unsigned recv_[8];
        int      lpos[8];
        #pragma unroll
        for (int i = 0; i < 8; ++i) {
            int e = e0 + i * 256;
            if (e < N_EDGES) {
                int dst = ei[(size_t)e << sh];
                if ((unsigned)dst >= N_NODES) dst = 0;
                int src = ei[(size_t)(N_EDGES + e) << sh];
                if ((unsigned)src >= N_NODES) src = 0;
                dstv[i]  = dst;
                recv_[i] = ((unsigned)f2b(wt[e]) << 16) | (unsigned)src;
                lpos[i]  = atomicAdd(&lcnt[dst / NODES_PER_GRP], 1);
            } else {
                dstv[i] = -1;
            }
        }
        __syncthreads();
        if (t < 8) gbase[t] = atomicAdd(&flag[16 + 16 * t], lcnt[t]);
        __syncthreads();

        #pragma unroll
        for (int i = 0; i < 8; ++i) {
            if (dstv[i] < 0) continue;
            int g   = dstv[i] / NODES_PER_GRP;
            int idx = gbase[g] + lpos[i];
            if (idx < QCAP) {
                int2 r; r.x = dstv[i]; r.y = (int)recv_[i];
                queue[(size_t)g * QCAP + idx] = r;
            }
        }
    }
}

// k2: XCD-local scatter, 4x ILP.
__global__ __launch_bounds__(256) void k_scat(const int2* __restrict__ queue,
                                              int* __restrict__ flag,
                                              int* __restrict__ fill,
                                              unsigned int* __restrict__ slots,
                                              int2* __restrict__ ovf) {
    const int g = blockIdx.x & 7;                    // == XCD (round-robin dispatch)
    const int b = blockIdx.x >> 3;                   // 0..SCAT_BPG-1
    int n = flag[16 + 16 * g]; if (n > QCAP) n = QCAP;
    const int2* q = queue + (size_t)g * QCAP;
    const int stride = SCAT_BPG * 256;

    int i = b * 256 + (int)threadIdx.x;
    for (; i + 3 * stride < n; i += 4 * stride) {
        int2 e0 = q[i];
        int2 e1 = q[i + stride];
        int2 e2 = q[i + 2 * stride];
        int2 e3 = q[i + 3 * stride];
        int p0 = atomicAdd(&fill[e0.x], 1);
        int p1 = atomicAdd(&fill[e1.x], 1);
        int p2 = atomicAdd(&fill[e2.x], 1);
        int p3 = atomicAdd(&fill[e3.x], 1);
        if (p0 < MAXD) slots[(size_t)e0.x * MAXD + p0] = (unsigned)e0.y;
        else { int op = atomicAdd(&flag[1], 1); if (op < OVF_CAP) ovf[op] = e0; }
        if (p1 < MAXD) slots[(size_t)e1.x * MAXD + p1] = (unsigned)e1.y;
        else { int op = atomicAdd(&flag[1], 1); if (op < OVF_CAP) ovf[op] = e1; }
        if (p2 < MAXD) slots[(size_t)e2.x * MAXD + p2] = (unsigned)e2.y;
        else { int op = atomicAdd(&flag[1], 1); if (op < OVF_CAP) ovf[op] = e2; }
        if (p3 < MAXD) slots[(size_t)e3.x * MAXD + p3] = (unsigned)e3.y;
        else { int op = atomicAdd(&flag[1], 1); if (op < OVF_CAP) ovf[op] = e3; }
    }
    for (; i < n; i += stride) {
        int2 ent = q[i];
        int pos = atomicAdd(&fill[ent.x], 1);
        if (pos < MAXD) slots[(size_t)ent.x * MAXD + pos] = (unsigned)ent.y;
        else { int op = atomicAdd(&flag[1], 1); if (op < OVF_CAP) ovf[op] = ent; }
    }
}

// k3: aggregation. XCD-grouped: block bid&7 handles nodes of partition group g
// (round-robin -> same XCD whose k_scat wrote those fill/slots lines -> L2-hot).
// Full 8-line straight-line unroll (deg<=32 always): 8 slot loads + 8 gathers
// all in flight, zero loop overhead. Invalid edges gather row 0 (L1-hot, w=0).
// Per-lane accumulation order identical to R6's loop -> bit-identical output.
#define AGG_FMA(w_, h_)                                                      \
    acc[0] = fmaf(w_, __uint_as_float((h_.x & 0xffffu) << 16), acc[0]);      \
    acc[1] = fmaf(w_, __uint_as_float(h_.x & 0xffff0000u),     acc[1]);      \
    acc[2] = fmaf(w_, __uint_as_float((h_.y & 0xffffu) << 16), acc[2]);      \
    acc[3] = fmaf(w_, __uint_as_float(h_.y & 0xffff0000u),     acc[3]);      \
    acc[4] = fmaf(w_, __uint_as_float((h_.z & 0xffffu) << 16), acc[4]);      \
    acc[5] = fmaf(w_, __uint_as_float(h_.z & 0xffff0000u),     acc[5]);      \
    acc[6] = fmaf(w_, __uint_as_float((h_.w & 0xffffu) << 16), acc[6]);      \
    acc[7] = fmaf(w_, __uint_as_float(h_.w & 0xffff0000u),     acc[7]);

__global__ __launch_bounds__(256) void k_agg(const int* __restrict__ fill,
                                             const unsigned int* __restrict__ slots,
                                             const unsigned int* __restrict__ hid,
                                             const int* __restrict__ flag,
                                             const int2* __restrict__ ovf,
                                             float* __restrict__ out) {
    const int wave = threadIdx.x >> 6;
    const int lane = threadIdx.x & 63;
    const int g    = blockIdx.x & 7;                // node group -> XCD g
    const int q    = blockIdx.x >> 3;               // 0..AGG_QPG-1
    const int loc  = q * 4 + wave;
    if (loc >= NODES_PER_GRP) return;               // wave-uniform tail exit
    const int node = g * NODES_PER_GRP + loc;
    const int grp  = lane >> 4;
    const int sub  = lane & 15;

    const int degf = fill[node];
    const int deg  = (degf > MAXD) ? MAXD : degf;
    const uint4* sl4 = (const uint4*)(slots + (size_t)node * MAXD);  // 8 lines

    float acc[8];
    #pragma unroll
    for (int j = 0; j < 8; ++j) acc[j] = 0.f;

    // all 8 slot lines + 8 gathers in flight (straight-line, no loop)
    uint4 L[8];
    #pragma unroll
    for (int k = 0; k < 8; ++k) L[k] = sl4[k];
    unsigned src_[8]; float w_[8];
    #pragma unroll
    for (int k = 0; k < 8; ++k) {
        unsigned rc = (grp < 2) ? (grp == 0 ? L[k].x : L[k].y)
                                : (grp == 2 ? L[k].z : L[k].w);
        const bool v = (k * 4 + grp) < deg;
        w_[k]   = v ? __uint_as_float(rc & 0xffff0000u) : 0.f;
        src_[k] = v ? (rc & 0xffffu) : 0u;
    }
    uint4 H[8];
    #pragma unroll
    for (int k = 0; k < 8; ++k) H[k] = *((const uint4*)(hid + (size_t)src_[k] * 64) + sub);
    #pragma unroll
    for (int k = 0; k < 8; ++k) { AGG_FMA(w_[k], H[k]) }

    // rare overflow edges folded in (entry i handled by lane-group i&3)
    if (degf > MAXD) {
        int n = flag[1]; if (n > OVF_CAP) n = OVF_CAP;
        for (int i = 0; i < n; ++i) {
            int2 r = ovf[i];
            if (r.x != node || (i & 3) != grp) continue;
            unsigned rec = (unsigned)r.y;
            float w = __uint_as_float(rec & 0xffff0000u);
            unsigned src = rec & 0xffffu;
            uint4 h = *((const uint4*)(hid + (size_t)src * 64) + sub);
            AGG_FMA(w, h)
        }
    }

    // combine the 4 lane-groups: butterfly over lane bits 4,5
    #pragma unroll
    for (int j = 0; j < 8; ++j) {
        float a = acc[j];
        a += __shfl_xor(a, 16, 64);
        a += __shfl_xor(a, 32, 64);
        acc[j] = a;
    }

    if (lane < 16) {
        float* o = out + (size_t)node * FEAT + sub * 8;
        *(float4*)(o)     = make_float4(acc[0], acc[1], acc[2], acc[3]);
        *(float4*)(o + 4) = make_float4(acc[4], acc[5], acc[6], acc[7]);
    }
}

extern "C" void kernel_launch(void* const* d_in, const int* in_sizes, int n_in,
                              void* d_out, int out_size, void* d_ws, size_t ws_size,
                              hipStream_t stream) {
    const float* x  = (const float*)d_in[0];
    const int*   ei = (const int*)d_in[1];
    const float* ew = (const float*)d_in[2];
    const float* W  = (const float*)d_in[3];
    const float* b  = (const float*)d_in[4];
    float* out = (float*)d_out;

    int*  flag = (int*)d_ws;                          // int[256], cursors padded
    int*  fill = flag + 256;
    int2* ovf  = (int2*)(fill + 50048);
    unsigned int* slots = (unsigned int*)(ovf + OVF_CAP);
    unsigned short* hidden = (unsigned short*)(slots + (size_t)N_NODES * MAXD);
    int2* queue = (int2*)(hidden + (size_t)N_NODES * FEAT);
    unsigned short* wbf = (unsigned short*)(queue + (size_t)8 * QCAP);

    k_prep <<<64, 256, 0, stream>>>(W, flag, wbf);    // zero cursors+fill, swizzled bf16 W
    k_fused<<<GEMM_BLOCKS + NCHUNK, 256, 0, stream>>>(x, wbf, b, hidden, ei, ew,
                                                      flag, queue);
    k_scat <<<8 * SCAT_BPG, 256, 0, stream>>>(queue, flag, fill, slots, ovf);
    k_agg  <<<8 * AGG_QPG, 256, 0, stream>>>(fill, slots, (const unsigned int*)hidden,
                                             flag, ovf, out);
}